// Round 9
// baseline (227.664 us; speedup 1.0000x reference)
//
#include <hip/hip_runtime.h>
#include <hip/hip_bf16.h>

#define N_NODES 100000
#define IN_DIM 128
#define OUT_DIM 32
#define NEG_SLOPE 0.01f
#define E_DEFAULT 1600000
#define BUCKET_SHIFT 7
#define BUCKET_SIZE 128
#define NB ((N_NODES + BUCKET_SIZE - 1) / BUCKET_SIZE)   // 782
#define ECHUNK 1024
#define PCAP 8192
#define WPAD 136   // bf16 LDS row stride for fc_w (16B-aligned, bank-balanced)

typedef __attribute__((ext_vector_type(8))) short bf16x8;
typedef __attribute__((ext_vector_type(4))) float f32x4;

__device__ __forceinline__ float bfu2f(unsigned int u16) {
    union { unsigned int i; float f; } v;
    v.i = u16 << 16;
    return v.f;
}
__device__ __forceinline__ unsigned short f2bfu(float f) {
    union { unsigned int i; float f; } v;
    v.f = f;
    unsigned int r = v.i + 0x7fffu + ((v.i >> 16) & 1u);  // RNE
    return (unsigned short)(r >> 16);
}

// K1 (MFMA + fused edge-chunk histogram). One wave = 16 nodes x 32 dims.
// Block b also histograms edges [b*ECHUNK, (b+1)*ECHUNK) into LDS bins and
// writes its blkcnt column. No early returns (clamped tile base; duplicate
// identical stores are benign).
__global__ __launch_bounds__(256) void k1_fused(
    const float* __restrict__ h,
    const float* __restrict__ fc_w,
    const float* __restrict__ attn_w,
    const int* __restrict__ dst,
    unsigned short* __restrict__ zbf,
    float* __restrict__ s_l,
    float* __restrict__ s_r,
    int* __restrict__ blkcnt,
    int E, int nblk, int nblkp) {
    __shared__ unsigned short wlds[OUT_DIM * WPAD];  // 8.5 KB bf16
    __shared__ float al[OUT_DIM], ar[OUT_DIM];
    __shared__ int bins[NB];

    const int t = threadIdx.x;
    // stage fc_w (32x128 fp32) -> bf16 LDS, padded rows; zero bins
    for (int i = t; i < NB; i += 256) bins[i] = 0;
    for (int i = t; i < OUT_DIM * IN_DIM / 4; i += 256) {
        const float4 v = ((const float4*)fc_w)[i];
        const int idx = i * 4;
        const int row = idx >> 7, col = idx & 127;
        unsigned short* p = &wlds[row * WPAD + col];
        p[0] = f2bfu(v.x); p[1] = f2bfu(v.y); p[2] = f2bfu(v.z); p[3] = f2bfu(v.w);
    }
    if (t < 2 * OUT_DIM) {
        if (t < OUT_DIM) al[t] = attn_w[t];
        else ar[t - OUT_DIM] = attn_w[t];
    }
    __syncthreads();

    // fused histogram of this block's edge chunk
    if (blockIdx.x < nblk) {
        const int e0 = blockIdx.x * ECHUNK;
#pragma unroll
        for (int k = 0; k < ECHUNK; k += 256) {
            const int e = e0 + k + t;
            if (e < E) atomicAdd(&bins[dst[e] >> BUCKET_SHIFT], 1);
        }
    }

    // MFMA z + scores
    const int wid = blockIdx.x * 4 + (t >> 6);
    int base = wid * 16;
    if (base > N_NODES - 16) base = N_NODES - 16;   // clamp: duplicates are benign
    const int lane = t & 63;
    const int row16 = lane & 15;
    const int quad = lane >> 4;

    f32x4 acc0 = {0.f, 0.f, 0.f, 0.f};
    f32x4 acc1 = {0.f, 0.f, 0.f, 0.f};
    const float* hrow = h + (size_t)(base + row16) * IN_DIM + quad * 8;
    const unsigned short* b0 = &wlds[row16 * WPAD + quad * 8];
    const unsigned short* b1 = &wlds[(row16 + 16) * WPAD + quad * 8];

#pragma unroll
    for (int s = 0; s < 4; ++s) {
        const float4 a0 = *(const float4*)(hrow + s * 32);
        const float4 a1 = *(const float4*)(hrow + s * 32 + 4);
        bf16x8 af;
        af[0] = (short)f2bfu(a0.x); af[1] = (short)f2bfu(a0.y);
        af[2] = (short)f2bfu(a0.z); af[3] = (short)f2bfu(a0.w);
        af[4] = (short)f2bfu(a1.x); af[5] = (short)f2bfu(a1.y);
        af[6] = (short)f2bfu(a1.z); af[7] = (short)f2bfu(a1.w);
        const bf16x8 bf0 = *(const bf16x8*)(b0 + s * 32);
        const bf16x8 bf1 = *(const bf16x8*)(b1 + s * 32);
        acc0 = __builtin_amdgcn_mfma_f32_16x16x32_bf16(af, bf0, acc0, 0, 0, 0);
        acc1 = __builtin_amdgcn_mfma_f32_16x16x32_bf16(af, bf1, acc1, 0, 0, 0);
    }

    const float al_lo = al[row16], al_hi = al[row16 + 16];
    const float ar_lo = ar[row16], ar_hi = ar[row16 + 16];
#pragma unroll
    for (int r = 0; r < 4; ++r) {
        const int node = base + quad * 4 + r;
        float p = acc0[r] * al_lo + acc1[r] * al_hi;
        float q = acc0[r] * ar_lo + acc1[r] * ar_hi;
        p += __shfl_xor(p, 1, 64); p += __shfl_xor(p, 2, 64);
        p += __shfl_xor(p, 4, 64); p += __shfl_xor(p, 8, 64);
        q += __shfl_xor(q, 1, 64); q += __shfl_xor(q, 2, 64);
        q += __shfl_xor(q, 4, 64); q += __shfl_xor(q, 8, 64);
        if (row16 == 0) { s_l[node] = p; s_r[node] = q; }
        zbf[(size_t)node * OUT_DIM + row16] = f2bfu(acc0[r]);
        zbf[(size_t)node * OUT_DIM + 16 + row16] = f2bfu(acc1[r]);
    }

    __syncthreads();
    if (blockIdx.x < nblk) {
        for (int i = t; i < NB; i += 256)
            blkcnt[(size_t)i * nblkp + blockIdx.x] = bins[i];
    }
}

// One wave per bin: coalesced row sum -> bsum (no atomics, no memset).
__global__ __launch_bounds__(256) void k_rowsum(
    const int* __restrict__ blkcnt, int* __restrict__ bsum, int nblk, int nblkp) {
    const int bin = blockIdx.x * 4 + (threadIdx.x >> 6);
    if (bin >= NB) return;
    const int lane = threadIdx.x & 63;
    const int* rowp = blkcnt + (size_t)bin * nblkp;
    int s = 0;
    for (int k = lane; k < nblk; k += 64) s += rowp[k];
#pragma unroll
    for (int m = 32; m; m >>= 1) s += __shfl_xor(s, m, 64);
    if (lane == 0) bsum[bin] = s;
}

// 1 block: exclusive scan over 782 bucket totals -> bstart.
__global__ __launch_bounds__(1024) void k_scan_top(
    const int* __restrict__ bsum, int* __restrict__ bstart) {
    __shared__ int sc[1024];
    const int t = threadIdx.x;
    const int v = (t < NB) ? bsum[t] : 0;
    sc[t] = v;
    __syncthreads();
    for (int off = 1; off < 1024; off <<= 1) {
        const int u = (t >= off) ? sc[t - off] : 0;
        __syncthreads();
        sc[t] += u;
        __syncthreads();
    }
    if (t < NB) bstart[t] = sc[t] - v;
    if (t == 1023) bstart[NB] = sc[1023];
}

// One wave per bin: lane-chunked row prefix -> per-(bin,blk) exclusive offsets.
__global__ __launch_bounds__(256) void k_scan_cols(
    int* __restrict__ blkcnt, const int* __restrict__ bstart,
    int nblk, int nblkp) {
    const int bin = blockIdx.x * 4 + (threadIdx.x >> 6);
    if (bin >= NB) return;
    const int lane = threadIdx.x & 63;
    const int c = (nblk + 63) >> 6;
    const int k0 = lane * c;
    int* rowp = blkcnt + (size_t)bin * nblkp;
    int s = 0;
    for (int j = 0; j < c; ++j) {
        const int k = k0 + j;
        if (k < nblk) s += rowp[k];
    }
    int incl = s;
    for (int off = 1; off < 64; off <<= 1) {
        const int u = __shfl_up(incl, off, 64);
        if (lane >= off) incl += u;
    }
    int run = bstart[bin] + incl - s;
    for (int j = 0; j < c; ++j) {
        const int k = k0 + j;
        if (k < nblk) {
            const int v = rowp[k];
            rowp[k] = run;
            run += v;
        }
    }
}

// Edges -> packed {ldst:7|src:17} into block-exclusive bucket runs.
__global__ __launch_bounds__(256) void k_scatter2(
    const int* __restrict__ src, const int* __restrict__ dst,
    const int* __restrict__ blkcnt, int* __restrict__ packed, int E, int nblkp) {
    __shared__ int ofs[NB];
    const int t = threadIdx.x;
    for (int i = t; i < NB; i += 256) ofs[i] = blkcnt[(size_t)i * nblkp + blockIdx.x];
    __syncthreads();
    const int e0 = blockIdx.x * ECHUNK;
#pragma unroll
    for (int k = 0; k < ECHUNK; k += 256) {
        const int e = e0 + k + t;
        if (e < E) {
            const int d = dst[e];
            const int bin = d >> BUCKET_SHIFT;
            const int pos = atomicAdd(&ofs[bin], 1);
            packed[pos] = ((d & (BUCKET_SIZE - 1)) << 17) | src[e];
        }
    }
}

// One block per bucket: stage in LDS, per-node count + scan -> nstart, then
// in-place permute to node-sorted src.
__global__ __launch_bounds__(256) void k_place(
    const int* __restrict__ bstart,
    int* __restrict__ packed,
    int* __restrict__ nstart) {
    __shared__ int pk[PCAP];
    __shared__ int cnt128[BUCKET_SIZE];
    __shared__ int pref[BUCKET_SIZE];
    __shared__ int cur[BUCKET_SIZE];

    const int bin = blockIdx.x;
    const int st = bstart[bin];
    int cnt = bstart[bin + 1] - st;
    if (cnt > PCAP) cnt = PCAP;
    const int t = threadIdx.x;

    if (t < BUCKET_SIZE) cnt128[t] = 0;
    __syncthreads();
    for (int i = t; i < cnt; i += 256) {
        const int p = packed[st + i];
        pk[i] = p;
        atomicAdd(&cnt128[p >> 17], 1);
    }
    __syncthreads();
    if (t < BUCKET_SIZE) pref[t] = cnt128[t];
    __syncthreads();
    for (int off = 1; off < BUCKET_SIZE; off <<= 1) {
        int u = 0;
        if (t < BUCKET_SIZE && t >= off) u = pref[t - off];
        __syncthreads();
        if (t < BUCKET_SIZE) pref[t] += u;
        __syncthreads();
    }
    if (t < BUCKET_SIZE) {
        const int excl = pref[t] - cnt128[t];
        nstart[bin * BUCKET_SIZE + t] = st + excl;
        cur[t] = excl;
    }
    __syncthreads();
    for (int i = t; i < cnt; i += 256) {
        const int p = pk[i];
        const int pos = st + atomicAdd(&cur[p >> 17], 1);
        packed[pos] = p & 0x1FFFF;
    }
}

// One wave per node: 16 edge streams x 4 dim-groups (8 bf16 via uint4/lane).
// Halved redundant exp vs 8-stream; chain depth ~deg/16 ~= 1.
__global__ __launch_bounds__(256) void k_gather16(
    const int* __restrict__ nstart,
    const int* __restrict__ esrc,
    const float* __restrict__ s_l,
    const float* __restrict__ s_r,
    const unsigned short* __restrict__ zbf,
    float* __restrict__ out) {
    const int gtid = blockIdx.x * 256 + threadIdx.x;
    const int n = gtid >> 6;
    if (n >= N_NODES) return;
    const int lane = gtid & 63;
    const int eslot = lane >> 2;
    const int dimg = lane & 3;

    const int st = nstart[n];
    const int cnt = nstart[n + 1] - st;
    const float sr_n = s_r[n];

    float a0 = 0.f, a1 = 0.f, a2 = 0.f, a3 = 0.f;
    float a4 = 0.f, a5 = 0.f, a6 = 0.f, a7 = 0.f, dn = 0.f;
    for (int i = eslot; i < cnt; i += 16) {
        const int es = esrc[st + i];
        float x = s_l[es] + sr_n;
        x = (x > 0.f) ? x : NEG_SLOPE * x;
        const float w = __expf(x);
        const uint4 zv = *(const uint4*)&zbf[(size_t)es * OUT_DIM + dimg * 8];
        a0 += w * bfu2f(zv.x & 0xffffu);
        a1 += w * bfu2f(zv.x >> 16);
        a2 += w * bfu2f(zv.y & 0xffffu);
        a3 += w * bfu2f(zv.y >> 16);
        a4 += w * bfu2f(zv.z & 0xffffu);
        a5 += w * bfu2f(zv.z >> 16);
        a6 += w * bfu2f(zv.w & 0xffffu);
        a7 += w * bfu2f(zv.w >> 16);
        dn += w;
    }
#pragma unroll
    for (int m = 4; m < 64; m <<= 1) {
        a0 += __shfl_xor(a0, m, 64);
        a1 += __shfl_xor(a1, m, 64);
        a2 += __shfl_xor(a2, m, 64);
        a3 += __shfl_xor(a3, m, 64);
        a4 += __shfl_xor(a4, m, 64);
        a5 += __shfl_xor(a5, m, 64);
        a6 += __shfl_xor(a6, m, 64);
        a7 += __shfl_xor(a7, m, 64);
        dn += __shfl_xor(dn, m, 64);
    }
    if (eslot == 0) {
        const float inv = (dn > 0.f) ? 1.f / dn : 0.f;
        float* op = &out[(size_t)n * OUT_DIM + dimg * 8];
        *(float4*)op = make_float4(a0 * inv, a1 * inv, a2 * inv, a3 * inv);
        *(float4*)(op + 4) = make_float4(a4 * inv, a5 * inv, a6 * inv, a7 * inv);
    }
}

// ---------------- atomic fallback path (known-passing) ----------

__global__ __launch_bounds__(256) void k1_z_scores(
    const float* __restrict__ h,
    const float* __restrict__ fc_w,
    const float* __restrict__ attn_w,
    unsigned short* __restrict__ zbf,
    float* __restrict__ s_l,
    float* __restrict__ s_r,
    float* __restrict__ denom,
    float* __restrict__ out) {
    __shared__ float wlds[OUT_DIM * IN_DIM];
    __shared__ float al[OUT_DIM], ar[OUT_DIM];

    const int tid = threadIdx.x;
    for (int i = tid; i < OUT_DIM * IN_DIM; i += 256) wlds[i] = fc_w[i];
    if (tid < OUT_DIM) {
        al[tid] = attn_w[tid];
        ar[tid] = attn_w[OUT_DIM + tid];
    }
    __syncthreads();

    const int node = blockIdx.x * 256 + tid;
    if (node >= N_NODES) return;

    float acc[OUT_DIM];
#pragma unroll
    for (int j = 0; j < OUT_DIM; ++j) acc[j] = 0.f;
    const float4* hp = (const float4*)(h + (size_t)node * IN_DIM);
#pragma unroll 4
    for (int kg = 0; kg < IN_DIM / 4; ++kg) {
        const float4 hv = hp[kg];
#pragma unroll
        for (int j = 0; j < OUT_DIM; ++j) {
            const float4 w = *(const float4*)&wlds[j * IN_DIM + kg * 4];
            acc[j] += hv.x * w.x + hv.y * w.y + hv.z * w.z + hv.w * w.w;
        }
    }
    float sl = 0.f, sr = 0.f;
#pragma unroll
    for (int j = 0; j < OUT_DIM; ++j) { sl += acc[j] * al[j]; sr += acc[j] * ar[j]; }
    s_l[node] = sl; s_r[node] = sr; denom[node] = 0.f;
    uint4* zp = (uint4*)(zbf + (size_t)node * OUT_DIM);
#pragma unroll
    for (int q = 0; q < 4; ++q) {
        uint4 pk;
        pk.x = (unsigned int)f2bfu(acc[8 * q + 0]) | ((unsigned int)f2bfu(acc[8 * q + 1]) << 16);
        pk.y = (unsigned int)f2bfu(acc[8 * q + 2]) | ((unsigned int)f2bfu(acc[8 * q + 3]) << 16);
        pk.z = (unsigned int)f2bfu(acc[8 * q + 4]) | ((unsigned int)f2bfu(acc[8 * q + 5]) << 16);
        pk.w = (unsigned int)f2bfu(acc[8 * q + 6]) | ((unsigned int)f2bfu(acc[8 * q + 7]) << 16);
        zp[q] = pk;
    }
    float4* op = (float4*)(out + (size_t)node * OUT_DIM);
    const float4 zero4 = make_float4(0.f, 0.f, 0.f, 0.f);
#pragma unroll
    for (int q = 0; q < 8; ++q) op[q] = zero4;
}

__global__ __launch_bounds__(256) void k3_edges(
    const int* __restrict__ src, const int* __restrict__ dst,
    const float* __restrict__ s_l, const float* __restrict__ s_r,
    const unsigned short* __restrict__ zbf,
    float* __restrict__ denom, float* __restrict__ out, int E) {
    const long long gid = (long long)blockIdx.x * 256 + threadIdx.x;
    const int e = (int)(gid >> 3);
    const int q = (int)(gid & 7);
    if (e >= E) return;
    const int s = src[e];
    const int d = dst[e];
    float x = s_l[s] + s_r[d];
    x = (x > 0.f) ? x : NEG_SLOPE * x;
    const float w = __expf(x);
    const uint2 zv = *(const uint2*)&zbf[(size_t)s * OUT_DIM + q * 4];
    float* op = &out[(size_t)d * OUT_DIM + q * 4];
    unsafeAtomicAdd(op + 0, w * bfu2f(zv.x & 0xffffu));
    unsafeAtomicAdd(op + 1, w * bfu2f(zv.x >> 16));
    unsafeAtomicAdd(op + 2, w * bfu2f(zv.y & 0xffffu));
    unsafeAtomicAdd(op + 3, w * bfu2f(zv.y >> 16));
    if (q == 0) unsafeAtomicAdd(&denom[d], w);
}

__global__ __launch_bounds__(256) void k4_finalize(
    const float* __restrict__ denom, float* __restrict__ out) {
    const int i = blockIdx.x * 256 + threadIdx.x;
    if (i >= N_NODES * OUT_DIM) return;
    const float dnm = denom[i >> 5];
    out[i] = (dnm > 0.f) ? out[i] / dnm : 0.f;
}

extern "C" void kernel_launch(void* const* d_in, const int* in_sizes, int n_in,
                              void* d_out, int out_size, void* d_ws, size_t ws_size,
                              hipStream_t stream) {
    const float* h      = (const float*)d_in[0];
    const int*   src    = (const int*)d_in[1];
    const int*   dst    = (const int*)d_in[2];
    const float* fc_w   = (const float*)d_in[3];
    const float* attn_w = (const float*)d_in[4];
    float* out = (float*)d_out;
    const int E = (in_sizes[1] > 0) ? in_sizes[1] : E_DEFAULT;
    const int nblk = (E + ECHUNK - 1) / ECHUNK;           // 1563
    const int nblkp = (nblk + 7) & ~7;                    // 1568

    char* ws = (char*)d_ws;
    size_t off = 0;
    unsigned short* zbf = (unsigned short*)(ws + off);
    off += (size_t)N_NODES * OUT_DIM * sizeof(unsigned short);       // 6.4 MB
    float* s_l = (float*)(ws + off); off += (size_t)N_NODES * 4;     // 0.4 MB
    float* s_r = (float*)(ws + off); off += (size_t)N_NODES * 4;     // 0.4 MB

    const size_t base = off;
    int* packed = (int*)(ws + off);  off += (size_t)E * 4;           // 6.4 MB
    int* blkcnt = (int*)(ws + off);  off += (size_t)NB * nblkp * 4;  // ~4.9 MB
    int* bstart = (int*)(ws + off);  off += ((size_t)NB + 1) * 4;
    int* nstart = (int*)(ws + off);  off += ((size_t)NB * BUCKET_SIZE + 1) * 4;
    int* bsum   = (int*)(ws + off);  off += (size_t)NB * 4;
    const size_t csr_total = off;    // ~19 MB
    float* denom = (float*)(ws + base);

    const bool use_csr = (ws_size >= csr_total);

    if (use_csr) {
        const int waves = (N_NODES + 15) / 16;                 // 6250
        const int blocks_z = (waves + 3) / 4;                  // 1563
        const int grid_k1 = (blocks_z > nblk) ? blocks_z : nblk;
        k1_fused<<<grid_k1, 256, 0, stream>>>(h, fc_w, attn_w, dst, zbf, s_l, s_r,
                                              blkcnt, E, nblk, nblkp);
        k_rowsum<<<(NB + 3) / 4, 256, 0, stream>>>(blkcnt, bsum, nblk, nblkp);
        k_scan_top<<<1, 1024, 0, stream>>>(bsum, bstart);
        k_scan_cols<<<(NB + 3) / 4, 256, 0, stream>>>(blkcnt, bstart, nblk, nblkp);
        k_scatter2<<<nblk, 256, 0, stream>>>(src, dst, blkcnt, packed, E, nblkp);
        k_place<<<NB, 256, 0, stream>>>(bstart, packed, nstart);
        const int blocks_g = (N_NODES * 64 + 255) / 256;
        k_gather16<<<blocks_g, 256, 0, stream>>>(nstart, packed, s_l, s_r, zbf, out);
    } else {
        const int blocks_k1 = (N_NODES + 255) / 256;
        k1_z_scores<<<blocks_k1, 256, 0, stream>>>(h, fc_w, attn_w, zbf, s_l, s_r, denom, out);
        const long long tot = (long long)E * 8;
        const int blocks_k3 = (int)((tot + 255) / 256);
        k3_edges<<<blocks_k3, 256, 0, stream>>>(src, dst, s_l, s_r, zbf, denom, out, E);
        const int blocks_k4 = (N_NODES * OUT_DIM + 255) / 256;
        k4_finalize<<<blocks_k4, 256, 0, stream>>>(denom, out);
    }
}